// Round 12
// baseline (397.929 us; speedup 1.0000x reference)
//
#include <hip/hip_runtime.h>
#include <hip/hip_bf16.h>
#include <hip/hip_fp8.h>

// Problem constants
#define NB 256
#define TT 64
#define DD 1280
#define WW 256
#define HH 512
#define VV 10000
#define VP 10112           // vocab padded to 79*128
#define NCT 79             // number of 128-col vocab tiles
#define MROWS (NB*TT)      // 16384 score rows

typedef short short8 __attribute__((ext_vector_type(8)));
typedef float f32x4 __attribute__((ext_vector_type(4)));
typedef int   int4v __attribute__((ext_vector_type(4)));
typedef int   int8v __attribute__((ext_vector_type(8)));

static __device__ __forceinline__ unsigned short f2bf(float x){
    unsigned int u = __float_as_uint(x);
    unsigned int r = u + 0x7FFFu + ((u >> 16) & 1u);   // RNE
    return (unsigned short)(r >> 16);
}
static __device__ __forceinline__ float bf2f(unsigned short u){
    return __uint_as_float(((unsigned int)u) << 16);
}
static __device__ __forceinline__ unsigned char f2f8(float x){
    __hip_fp8_e4m3 q(x);                                // OCP e4m3fn
    return (unsigned char)q.__x;
}
// fp4 e2m1 encode of x (round to nearest on the grid {0,.5,1,1.5,2,3,4,6})
static __device__ __forceinline__ unsigned enc4(float x){
    unsigned s = (x < 0.f) ? 8u : 0u;
    float a = fabsf(x);
    unsigned m;
    if      (a < 0.25f) m = 0;
    else if (a < 0.75f) m = 1;
    else if (a < 1.25f) m = 2;
    else if (a < 1.75f) m = 3;
    else if (a < 2.5f)  m = 4;
    else if (a < 3.5f)  m = 5;
    else if (a < 5.0f)  m = 6;
    else                m = 7;
    return s | m;
}
static __device__ __forceinline__ void gload16b(const unsigned char* g, unsigned char* l){
    __builtin_amdgcn_global_load_lds(
        (const __attribute__((address_space(1))) void*)g,
        (__attribute__((address_space(3))) void*)l, 16, 0, 0);
}

// ---------- prep: transpose + convert: in[R][C] f32 -> out[Cp][R] bf16 (zero-pad C..Cp) ----------
__global__ __launch_bounds__(256) void k_transpose_bf(const float* __restrict__ in,
                                                      unsigned short* __restrict__ out,
                                                      int R, int C, int Cp){
    __shared__ unsigned short tile[64][17];
    int r0 = blockIdx.y*16, c0 = blockIdx.x*64;
    int tid = threadIdx.x;
    int c = tid & 63, rr = tid >> 6;
    #pragma unroll
    for (int j = 0; j < 4; ++j){
        int r = rr + j*4;
        unsigned short v = 0;
        if (r0 + r < R && c0 + c < C) v = f2bf(in[(size_t)(r0+r)*C + c0 + c]);
        tile[c][r] = v;
    }
    __syncthreads();
    int rw = tid & 15, cw = tid >> 4;
    #pragma unroll
    for (int j = 0; j < 4; ++j){
        int c2 = cw + j*16;
        if (c0 + c2 < Cp && r0 + rw < R)
            out[(size_t)(c0+c2)*R + r0 + rw] = tile[c2][rw];
    }
}

// ---------- prep: transpose + convert: in[R][C] f32 -> out[Cp][R] fp8 e4m3 (zero-pad) ----------
__global__ __launch_bounds__(256) void k_transpose_f8(const float* __restrict__ in,
                                                      unsigned char* __restrict__ out,
                                                      int R, int C, int Cp){
    __shared__ unsigned char tile[64][20];
    int r0 = blockIdx.y*16, c0 = blockIdx.x*64;
    int tid = threadIdx.x;
    int c = tid & 63, rr = tid >> 6;
    #pragma unroll
    for (int j = 0; j < 4; ++j){
        int r = rr + j*4;
        unsigned char v = 0;
        if (r0 + r < R && c0 + c < C) v = f2f8(in[(size_t)(r0+r)*C + c0 + c]);
        tile[c][r] = v;
    }
    __syncthreads();
    int rw = tid & 15, cw = tid >> 4;
    #pragma unroll
    for (int j = 0; j < 4; ++j){
        int c2 = cw + j*16;
        if (c0 + c2 < Cp && r0 + rw < R)
            out[(size_t)(c0+c2)*R + r0 + rw] = tile[c2][rw];
    }
}

// ---------- prep: Wh[k][c] f32 -> WhT4[c][k/2] packed fp4 e2m1, value = code * 2^-5 ----------
__global__ __launch_bounds__(512) void k_wh4(const float* __restrict__ Wh,
                                             unsigned char* __restrict__ WhT4){
    int j = blockIdx.x;          // k-pair index 0..255
    int col = threadIdx.x;       // 0..511
    float w0 = Wh[(size_t)(2*j  )*HH + col] * 32.0f;
    float w1 = Wh[(size_t)(2*j+1)*HH + col] * 32.0f;
    WhT4[(size_t)col*256 + j] = (unsigned char)(enc4(w0) | (enc4(w1) << 4));
}

// ---------- bias pad: bop[i] = b_out[i] or -30000 ----------
__global__ __launch_bounds__(256) void k_biaspad(const float* __restrict__ bo, float* __restrict__ bop){
    int i = blockIdx.x*256 + threadIdx.x;
    if (i < VP) bop[i] = (i < VV) ? bo[i] : -30000.0f;
}

// ---------- h0 = features @ W_proj + b_proj (fp32) ----------
__global__ __launch_bounds__(512) void k_h0(const float* __restrict__ feat,
                                            const float* __restrict__ Wp,
                                            const float* __restrict__ bp,
                                            float* __restrict__ h0){
    int n0 = blockIdx.x*4;
    int h = threadIdx.x;
    float a0=0.f,a1=0.f,a2=0.f,a3=0.f;
    for (int d = 0; d < DD; ++d){
        float w = Wp[(size_t)d*HH + h];
        a0 += feat[(size_t)(n0+0)*DD + d]*w;
        a1 += feat[(size_t)(n0+1)*DD + d]*w;
        a2 += feat[(size_t)(n0+2)*DD + d]*w;
        a3 += feat[(size_t)(n0+3)*DD + d]*w;
    }
    float bb = bp[h];
    h0[(size_t)(n0+0)*HH+h] = a0+bb;
    h0[(size_t)(n0+1)*HH+h] = a1+bb;
    h0[(size_t)(n0+2)*HH+h] = a2+bb;
    h0[(size_t)(n0+3)*HH+h] = a3+bb;
}

// ---------- E2[v][h] = sum_w W_embed[v][w] * Wx[w][h] + b[h]  (bf16 MFMA, bf16 out) ----------
__global__ __launch_bounds__(256) void k_e2(const float* __restrict__ We,
                                            const unsigned short* __restrict__ WxT,
                                            const float* __restrict__ bias,
                                            unsigned short* __restrict__ E2b){
    int lane = threadIdx.x & 63;
    int wv   = threadIdx.x >> 6;           // 0..3
    int l15 = lane & 15, lhi = lane >> 4;
    int rbase = blockIdx.x*64 + wv*16;
    int arow = rbase + l15; if (arow > VV-1) arow = VV-1;
    short8 a[8];
    #pragma unroll
    for (int kk = 0; kk < 8; ++kk){
        const float* src = We + (size_t)arow*WW + kk*32 + lhi*8;
        float4 f0 = *reinterpret_cast<const float4*>(src);
        float4 f1 = *reinterpret_cast<const float4*>(src + 4);
        short8 v;
        v[0]=(short)f2bf(f0.x); v[1]=(short)f2bf(f0.y); v[2]=(short)f2bf(f0.z); v[3]=(short)f2bf(f0.w);
        v[4]=(short)f2bf(f1.x); v[5]=(short)f2bf(f1.y); v[6]=(short)f2bf(f1.z); v[7]=(short)f2bf(f1.w);
        a[kk] = v;
    }
    for (int ct = 0; ct < 32; ++ct){
        int c0 = ct*16;
        f32x4 acc = {0.f,0.f,0.f,0.f};
        #pragma unroll
        for (int kk = 0; kk < 8; ++kk){
            short8 b = *reinterpret_cast<const short8*>(WxT + (size_t)(c0 + l15)*WW + kk*32 + lhi*8);
            acc = __builtin_amdgcn_mfma_f32_16x16x32_bf16(a[kk], b, acc, 0, 0, 0);
        }
        float bb = bias[c0 + l15];
        #pragma unroll
        for (int r = 0; r < 4; ++r){
            int row = rbase + lhi*4 + r;
            if (row < VV) E2b[(size_t)row*HH + c0 + l15] = f2bf(acc[r] + bb);
        }
    }
}

// ---------- RNN v3: 1 sample per block, 256 blocks = ALL CUs (unchanged, round 11) ----------
__global__ __launch_bounds__(512, 2) void k_rnn(const float* __restrict__ h0,
                                                const unsigned char* __restrict__ WhT4,
                                                const unsigned short* __restrict__ E2b,
                                                const int* __restrict__ caps,
                                                unsigned char* __restrict__ hA8){
    __shared__ __align__(32) unsigned char hl[2][HH];   // fp8 h, double-buffered (1 KB)
    int tid = threadIdx.x;
    int lane = tid & 63, wv = tid >> 6;      // 8 waves
    int l15 = lane & 15, lhi = lane >> 4;
    int n = blockIdx.x;
    int c0w = wv*64;                         // 64 cols per wave
    int mycol = c0w + lane;                  // col this lane finishes (ct==lhi)

    // B fragments: Wh fp4, register-resident (pinned): 4 ct x 4 kt x 16 B
    int4v b[4][4];
    #pragma unroll
    for (int ct = 0; ct < 4; ++ct){
        int col = c0w + ct*16 + l15;
        #pragma unroll
        for (int kt = 0; kt < 4; ++kt){
            b[ct][kt] = *reinterpret_cast<const int4v*>(WhT4 + (size_t)col*256 + kt*64 + lhi*16);
            asm volatile("" : "+v"(b[ct][kt]));   // opaque: no remat / re-stream
        }
    }
    // init hl[0] from h0 (fp32 -> fp8), one col per thread
    hl[0][tid] = f2f8(h0[(size_t)n*HH + tid]);
    __syncthreads();
    int cur = 0;
    for (int t = 0; t < TT; ++t){
        int tok = caps[n*(TT+1) + t];
        unsigned short xv = E2b[(size_t)tok*HH + mycol];
        int8v a[4];
        #pragma unroll
        for (int kt = 0; kt < 4; ++kt)
            a[kt] = *reinterpret_cast<const int8v*>(&hl[cur][kt*128 + lhi*32]);
        f32x4 acc[4];
        #pragma unroll
        for (int ct = 0; ct < 4; ++ct){
            acc[ct] = (f32x4){0.f,0.f,0.f,0.f};
            #pragma unroll
            for (int kt = 0; kt < 4; ++kt){
                int8v bb = __builtin_shufflevector(b[ct][kt], b[ct][kt], 0,1,2,3,0,1,2,3);
                acc[ct] = __builtin_amdgcn_mfma_scale_f32_16x16x128_f8f6f4(
                    a[kt], bb, acc[ct],
                    0, 4,                        // cbsz=fp8(A), blgp=fp4(B)
                    0, (int)0x7F7F7F7F,          // A scale 2^0
                    0, (int)0x7A7A7A7A);         // B scale 2^-5
            }
        }
        float v = (lhi == 0) ? acc[0][0] : (lhi == 1) ? acc[1][0]
                : (lhi == 2) ? acc[2][0] : acc[3][0];
        float x = v + bf2f(xv);
        float e = __expf(2.f*x);
        float th = 1.f - 2.f/(e + 1.f);          // tanh(x), saturates correctly
        unsigned char hv = f2f8(th);
        hl[cur^1][mycol] = hv;
        hA8[((size_t)n*TT + t)*HH + mycol] = hv;
        __syncthreads();
        cur ^= 1;
    }
}

// ---------- scores: MX-fp8 GEMM, WAVE-PRIVATE staging (no K-loop barriers) ----------
// Each wave stages ITS OWN 64 A-rows + 64 B-cols per kt into a private 16 KB LDS
// region (halves duplicated x2 across waves — L2 has headroom), waits with a
// wave-level s_waitcnt vmcnt(0) instead of __syncthreads. A stalled wave no longer
// blocks the other 7 resident waves -> MFMA pipe stays fed. 2 barriers total
// (around the cross-wc epilogue reduce). Fragment math/swizzle unchanged.
__global__ __launch_bounds__(256) void k_scores(const unsigned char* __restrict__ hA8,
                                                const unsigned char* __restrict__ WoT8p,
                                                const float* __restrict__ bop,
                                                const int* __restrict__ caps,
                                                float* __restrict__ pps,   // [NCT][MROWS]
                                                float* __restrict__ pts){  // [NCT][MROWS]
    __shared__ unsigned char As[4*64*128];   // 32 KB: per-wave 8 KB A half
    __shared__ unsigned char Bs[4*64*128];   // 32 KB: per-wave 8 KB B half
    int bid = blockIdx.x;
    int x = bid & 7;                 // XCD (blocks round-robin across XCDs)
    int local = bid >> 3;            // 0..1263
    int ct = local >> 4;             // ct-major within XCD
    int rt = x*16 + (local & 15);    // rt-minor: 16 consecutive row-tiles per XCD

    int tid = threadIdx.x;
    int lane = tid & 63, wv = tid >> 6;
    int l15 = lane & 15, lhi = lane >> 4;
    int wr = wv >> 1, wc = wv & 1;
    unsigned char* Aw = As + wv*8192;
    unsigned char* Bw = Bs + wv*8192;
    const size_t Abase = ((size_t)rt*128 + wr*64)*HH;   // this wave's 64 A rows
    const size_t Bbase = ((size_t)ct*128 + wc*64)*HH;   // this wave's 64 B cols

    // staging geometry: 512 chunks per 8 KB half, 8 per lane (i=0..7):
    // chunk = i*64 + lane -> rowloc = chunk>>3, col-chunk pre-swizzled.
    unsigned srow[8], selem[8];
    #pragma unroll
    for (int i = 0; i < 8; ++i){
        unsigned chunk = (unsigned)(i*64 + lane);
        srow[i]  = chunk >> 3;                          // 0..63
        selem[i] = ((chunk & 7u) ^ (srow[i] & 7u)) * 16u;
    }

    f32x4 acc[4][4];
    #pragma unroll
    for (int m = 0; m < 4; ++m)
        #pragma unroll
        for (int n = 0; n < 4; ++n)
            acc[m][n] = (f32x4){0.f,0.f,0.f,0.f};

    for (int kt = 0; kt < 4; ++kt){
        #pragma unroll
        for (int i = 0; i < 8; ++i){
            gload16b(hA8   + Abase + (size_t)srow[i]*HH + kt*128 + selem[i], Aw + i*1024);
            gload16b(WoT8p + Bbase + (size_t)srow[i]*HH + kt*128 + selem[i], Bw + i*1024);
        }
        asm volatile("s_waitcnt vmcnt(0)" ::: "memory");   // wave-level, no barrier
        int8v af[4], bf[4];
        #pragma unroll
        for (int m = 0; m < 4; ++m){
            unsigned row = (unsigned)(m*16 + l15);          // wave-local row 0..63
            int4v c0 = *reinterpret_cast<const int4v*>(Aw + row*128 + (((unsigned)(lhi*2+0) ^ (row&7))*16));
            int4v c1 = *reinterpret_cast<const int4v*>(Aw + row*128 + (((unsigned)(lhi*2+1) ^ (row&7))*16));
            af[m] = __builtin_shufflevector(c0, c1, 0,1,2,3,4,5,6,7);
        }
        #pragma unroll
        for (int n = 0; n < 4; ++n){
            unsigned col = (unsigned)(n*16 + l15);          // wave-local col 0..63
            int4v c0 = *reinterpret_cast<const int4v*>(Bw + col*128 + (((unsigned)(lhi*2+0) ^ (col&7))*16));
            int4v c1 = *reinterpret_cast<const int4v*>(Bw + col*128 + (((unsigned)(lhi*2+1) ^ (col&7))*16));
            bf[n] = __builtin_shufflevector(c0, c1, 0,1,2,3,4,5,6,7);
        }
        #pragma unroll
        for (int m = 0; m < 4; ++m)
            #pragma unroll
            for (int n = 0; n < 4; ++n)
                acc[m][n] = __builtin_amdgcn_mfma_scale_f32_16x16x128_f8f6f4(
                    af[m], bf[n], acc[m][n],
                    0, 0,
                    0, (int)0x7F7F7F7F,
                    0, (int)0x7F7F7F7F);
        // ds_reads of this kt fully returned before next kt's gloads overwrite Aw/Bw
        asm volatile("s_waitcnt lgkmcnt(0)" ::: "memory");
    }

    int tg[4][4];
    float srun[4][4], ts[4][4];
    #pragma unroll
    for (int m = 0; m < 4; ++m)
        #pragma unroll
        for (int r = 0; r < 4; ++r){
            int gr = rt*128 + wr*64 + m*16 + lhi*4 + r;
            tg[m][r] = caps[(gr >> 6)*(TT+1) + (gr & 63) + 1];
            srun[m][r] = 0.f; ts[m][r] = 0.f;
        }
    #pragma unroll
    for (int n = 0; n < 4; ++n){
        int colg = ct*128 + wc*64 + n*16 + l15;
        float bb = bop[colg];
        #pragma unroll
        for (int m = 0; m < 4; ++m)
            #pragma unroll
            for (int r = 0; r < 4; ++r){
                float sc = acc[m][n][r] + bb;
                srun[m][r] += __expf(sc);
                if (tg[m][r] == colg) ts[m][r] += sc;
            }
    }
    #pragma unroll
    for (int off = 1; off < 16; off <<= 1)
        #pragma unroll
        for (int m = 0; m < 4; ++m)
            #pragma unroll
            for (int r = 0; r < 4; ++r){
                srun[m][r] += __shfl_xor(srun[m][r], off, 64);
                ts[m][r]   += __shfl_xor(ts[m][r],   off, 64);
            }
    // cross-wc reduction: waves (wr,0) and (wr,1) hold partials for the SAME rows.
    float* red = (float*)As;   // 256 floats in wave-0's region
    __syncthreads();           // all waves done with their K-loop LDS reads
    if (wc == 1 && l15 == 0){
        #pragma unroll
        for (int m = 0; m < 4; ++m)
            #pragma unroll
            for (int r = 0; r < 4; ++r){
                int ri = wr*64 + m*16 + lhi*4 + r;
                red[ri]       = srun[m][r];
                red[128 + ri] = ts[m][r];
            }
    }
    __syncthreads();
    if (wc == 0 && l15 == 0){
        #pragma unroll
        for (int m = 0; m < 4; ++m)
            #pragma unroll
            for (int r = 0; r < 4; ++r){
                int ri = wr*64 + m*16 + lhi*4 + r;
                int gr = rt*128 + ri;
                pps[(size_t)ct*MROWS + gr] = srun[m][r] + red[ri];
                pts[(size_t)ct*MROWS + gr] = ts[m][r]   + red[128 + ri];
            }
    }
}

// ---------- loss stage 1: per-row nll, block partial sums (64 blocks x 256 thr) ----------
__global__ __launch_bounds__(256) void k_loss1(const float* __restrict__ pps,
                                               const float* __restrict__ pts,
                                               const int* __restrict__ caps,
                                               float* __restrict__ bsum){
    __shared__ float red[256];
    int tid = threadIdx.x;
    int row = blockIdx.x*256 + tid;
    float s = 0.f, t0 = 0.f;
    for (int ct = 0; ct < NCT; ++ct){
        s  += pps[(size_t)ct*MROWS + row];
        t0 += pts[(size_t)ct*MROWS + row];
    }
    int tgt = caps[(row >> 6)*(TT+1) + (row & 63) + 1];
    red[tid] = (tgt != 0) ? (__logf(s) - t0) : 0.f;
    __syncthreads();
    for (int off = 128; off > 0; off >>= 1){
        if (tid < off) red[tid] += red[tid+off];
        __syncthreads();
    }
    if (tid == 0) bsum[blockIdx.x] = red[0];
}

// ---------- loss stage 2: final sum / N ----------
__global__ __launch_bounds__(64) void k_loss2(const float* __restrict__ bsum, float* __restrict__ out){
    __shared__ float red[64];
    int tid = threadIdx.x;
    red[tid] = bsum[tid];
    __syncthreads();
    for (int off = 32; off > 0; off >>= 1){
        if (tid < off) red[tid] += red[tid+off];
        __syncthreads();
    }
    if (tid == 0) out[0] = red[0] / (float)NB;
}

extern "C" void kernel_launch(void* const* d_in, const int* in_sizes, int n_in,
                              void* d_out, int out_size, void* d_ws, size_t ws_size,
                              hipStream_t stream) {
    const float* features = (const float*)d_in[0];
    const int*   captions = (const int*)  d_in[1];
    const float* W_proj   = (const float*)d_in[2];
    const float* b_proj   = (const float*)d_in[3];
    const float* W_embed  = (const float*)d_in[4];
    const float* Wx       = (const float*)d_in[5];
    const float* Wh       = (const float*)d_in[6];
    const float* b_       = (const float*)d_in[7];
    const float* W_out    = (const float*)d_in[8];
    const float* b_out    = (const float*)d_in[9];
    float* out = (float*)d_out;

    char* ws = (char*)d_ws;
    // byte offsets (256-aligned)
    unsigned short* E2b   = (unsigned short*)(ws + 0);           // 10000*512*2 = 10,240,000
    float*          h0    = (float*)         (ws + 10240000);    // 256*512*4   =    524,288
    unsigned char*  WhT4  = (unsigned char*) (ws + 10764288);    // 512*256     =    131,072
    unsigned short* WxT   = (unsigned short*)(ws + 10895360);    // 512*256*2   =    262,144
    unsigned char*  WoT8p = (unsigned char*) (ws + 11157504);    // 10112*512*1 =  5,177,344
    float*          bop   = (float*)         (ws + 16334848);    // 10112*4     =     40,448
    unsigned char*  hA8   = (unsigned char*) (ws + 16375296);    // 16384*512*1 =  8,388,608
    float*          pps   = (float*)         (ws + 24763904);    // 79*16384*4  =  5,177,344
    float*          pts   = (float*)         (ws + 29941248);    // 79*16384*4  =  5,177,344
    float*          bsum  = (float*)         (ws + 35118592);    // 64*4        =        256
    if (ws_size < 35118848u) return;

    k_transpose_bf<<<dim3(8, 16),  256, 0, stream>>>(Wx,    WxT,   WW, HH, HH);
    k_wh4<<<256, 512, 0, stream>>>(Wh, WhT4);
    k_transpose_f8<<<dim3(158,32), 256, 0, stream>>>(W_out, WoT8p, HH, VV, VP);
    k_biaspad<<<40, 256, 0, stream>>>(b_out, bop);
    k_h0<<<NB/4, 512, 0, stream>>>(features, W_proj, b_proj, h0);
    k_e2<<<157, 256, 0, stream>>>(W_embed, WxT, b_, E2b);
    k_rnn<<<NB, 512, 0, stream>>>(h0, WhT4, E2b, captions, hA8);
    k_scores<<<128*NCT, 256, 0, stream>>>(hA8, WoT8p, bop, captions, pps, pts);
    k_loss1<<<64, 256, 0, stream>>>(pps, pts, captions, bsum);
    k_loss2<<<1, 64, 0, stream>>>(bsum, out);
}

// Round 13
// 387.063 us; speedup vs baseline: 1.0281x; 1.0281x over previous
//
#include <hip/hip_runtime.h>
#include <hip/hip_bf16.h>
#include <hip/hip_fp8.h>

// Problem constants
#define NB 256
#define TT 64
#define DD 1280
#define WW 256
#define HH 512
#define VV 10000
#define VP 10112           // vocab padded to 79*128
#define NCT 79             // number of 128-col vocab tiles
#define MROWS (NB*TT)      // 16384 score rows

typedef short short8 __attribute__((ext_vector_type(8)));
typedef float f32x4 __attribute__((ext_vector_type(4)));
typedef int   int4v __attribute__((ext_vector_type(4)));
typedef int   int8v __attribute__((ext_vector_type(8)));

static __device__ __forceinline__ unsigned short f2bf(float x){
    unsigned int u = __float_as_uint(x);
    unsigned int r = u + 0x7FFFu + ((u >> 16) & 1u);   // RNE
    return (unsigned short)(r >> 16);
}
static __device__ __forceinline__ float bf2f(unsigned short u){
    return __uint_as_float(((unsigned int)u) << 16);
}
static __device__ __forceinline__ unsigned char f2f8(float x){
    __hip_fp8_e4m3 q(x);                                // OCP e4m3fn
    return (unsigned char)q.__x;
}
// fp4 e2m1 encode of x (round to nearest on the grid {0,.5,1,1.5,2,3,4,6})
static __device__ __forceinline__ unsigned enc4(float x){
    unsigned s = (x < 0.f) ? 8u : 0u;
    float a = fabsf(x);
    unsigned m;
    if      (a < 0.25f) m = 0;
    else if (a < 0.75f) m = 1;
    else if (a < 1.25f) m = 2;
    else if (a < 1.75f) m = 3;
    else if (a < 2.5f)  m = 4;
    else if (a < 3.5f)  m = 5;
    else if (a < 5.0f)  m = 6;
    else                m = 7;
    return s | m;
}
static __device__ __forceinline__ void gload16b(const unsigned char* g, unsigned char* l){
    __builtin_amdgcn_global_load_lds(
        (const __attribute__((address_space(1))) void*)g,
        (__attribute__((address_space(3))) void*)l, 16, 0, 0);
}

// ---------- prep: transpose + convert: in[R][C] f32 -> out[Cp][R] bf16 (zero-pad C..Cp) ----------
__global__ __launch_bounds__(256) void k_transpose_bf(const float* __restrict__ in,
                                                      unsigned short* __restrict__ out,
                                                      int R, int C, int Cp){
    __shared__ unsigned short tile[64][17];
    int r0 = blockIdx.y*16, c0 = blockIdx.x*64;
    int tid = threadIdx.x;
    int c = tid & 63, rr = tid >> 6;
    #pragma unroll
    for (int j = 0; j < 4; ++j){
        int r = rr + j*4;
        unsigned short v = 0;
        if (r0 + r < R && c0 + c < C) v = f2bf(in[(size_t)(r0+r)*C + c0 + c]);
        tile[c][r] = v;
    }
    __syncthreads();
    int rw = tid & 15, cw = tid >> 4;
    #pragma unroll
    for (int j = 0; j < 4; ++j){
        int c2 = cw + j*16;
        if (c0 + c2 < Cp && r0 + rw < R)
            out[(size_t)(c0+c2)*R + r0 + rw] = tile[c2][rw];
    }
}

// ---------- prep: transpose + convert: in[R][C] f32 -> out[Cp][R] fp8 e4m3 (zero-pad) ----------
__global__ __launch_bounds__(256) void k_transpose_f8(const float* __restrict__ in,
                                                      unsigned char* __restrict__ out,
                                                      int R, int C, int Cp){
    __shared__ unsigned char tile[64][20];
    int r0 = blockIdx.y*16, c0 = blockIdx.x*64;
    int tid = threadIdx.x;
    int c = tid & 63, rr = tid >> 6;
    #pragma unroll
    for (int j = 0; j < 4; ++j){
        int r = rr + j*4;
        unsigned char v = 0;
        if (r0 + r < R && c0 + c < C) v = f2f8(in[(size_t)(r0+r)*C + c0 + c]);
        tile[c][r] = v;
    }
    __syncthreads();
    int rw = tid & 15, cw = tid >> 4;
    #pragma unroll
    for (int j = 0; j < 4; ++j){
        int c2 = cw + j*16;
        if (c0 + c2 < Cp && r0 + rw < R)
            out[(size_t)(c0+c2)*R + r0 + rw] = tile[c2][rw];
    }
}

// ---------- prep: Wh[k][c] f32 -> WhT4[c][k/2] packed fp4 e2m1, value = code * 2^-5 ----------
__global__ __launch_bounds__(512) void k_wh4(const float* __restrict__ Wh,
                                             unsigned char* __restrict__ WhT4){
    int j = blockIdx.x;          // k-pair index 0..255
    int col = threadIdx.x;       // 0..511
    float w0 = Wh[(size_t)(2*j  )*HH + col] * 32.0f;
    float w1 = Wh[(size_t)(2*j+1)*HH + col] * 32.0f;
    WhT4[(size_t)col*256 + j] = (unsigned char)(enc4(w0) | (enc4(w1) << 4));
}

// ---------- bias pad: bop[i] = b_out[i] or -30000 ----------
__global__ __launch_bounds__(256) void k_biaspad(const float* __restrict__ bo, float* __restrict__ bop){
    int i = blockIdx.x*256 + threadIdx.x;
    if (i < VP) bop[i] = (i < VV) ? bo[i] : -30000.0f;
}

// ---------- h0 = features @ W_proj + b_proj (fp32) ----------
__global__ __launch_bounds__(512) void k_h0(const float* __restrict__ feat,
                                            const float* __restrict__ Wp,
                                            const float* __restrict__ bp,
                                            float* __restrict__ h0){
    int n0 = blockIdx.x*4;
    int h = threadIdx.x;
    float a0=0.f,a1=0.f,a2=0.f,a3=0.f;
    for (int d = 0; d < DD; ++d){
        float w = Wp[(size_t)d*HH + h];
        a0 += feat[(size_t)(n0+0)*DD + d]*w;
        a1 += feat[(size_t)(n0+1)*DD + d]*w;
        a2 += feat[(size_t)(n0+2)*DD + d]*w;
        a3 += feat[(size_t)(n0+3)*DD + d]*w;
    }
    float bb = bp[h];
    h0[(size_t)(n0+0)*HH+h] = a0+bb;
    h0[(size_t)(n0+1)*HH+h] = a1+bb;
    h0[(size_t)(n0+2)*HH+h] = a2+bb;
    h0[(size_t)(n0+3)*HH+h] = a3+bb;
}

// ---------- E2[v][h] = sum_w W_embed[v][w] * Wx[w][h] + b[h]  (bf16 MFMA, bf16 out) ----------
__global__ __launch_bounds__(256) void k_e2(const float* __restrict__ We,
                                            const unsigned short* __restrict__ WxT,
                                            const float* __restrict__ bias,
                                            unsigned short* __restrict__ E2b){
    int lane = threadIdx.x & 63;
    int wv   = threadIdx.x >> 6;           // 0..3
    int l15 = lane & 15, lhi = lane >> 4;
    int rbase = blockIdx.x*64 + wv*16;
    int arow = rbase + l15; if (arow > VV-1) arow = VV-1;
    short8 a[8];
    #pragma unroll
    for (int kk = 0; kk < 8; ++kk){
        const float* src = We + (size_t)arow*WW + kk*32 + lhi*8;
        float4 f0 = *reinterpret_cast<const float4*>(src);
        float4 f1 = *reinterpret_cast<const float4*>(src + 4);
        short8 v;
        v[0]=(short)f2bf(f0.x); v[1]=(short)f2bf(f0.y); v[2]=(short)f2bf(f0.z); v[3]=(short)f2bf(f0.w);
        v[4]=(short)f2bf(f1.x); v[5]=(short)f2bf(f1.y); v[6]=(short)f2bf(f1.z); v[7]=(short)f2bf(f1.w);
        a[kk] = v;
    }
    for (int ct = 0; ct < 32; ++ct){
        int c0 = ct*16;
        f32x4 acc = {0.f,0.f,0.f,0.f};
        #pragma unroll
        for (int kk = 0; kk < 8; ++kk){
            short8 b = *reinterpret_cast<const short8*>(WxT + (size_t)(c0 + l15)*WW + kk*32 + lhi*8);
            acc = __builtin_amdgcn_mfma_f32_16x16x32_bf16(a[kk], b, acc, 0, 0, 0);
        }
        float bb = bias[c0 + l15];
        #pragma unroll
        for (int r = 0; r < 4; ++r){
            int row = rbase + lhi*4 + r;
            if (row < VV) E2b[(size_t)row*HH + c0 + l15] = f2bf(acc[r] + bb);
        }
    }
}

// ---------- RNN v3: 1 sample per block, 256 blocks = ALL CUs (unchanged, round 11) ----------
__global__ __launch_bounds__(512, 2) void k_rnn(const float* __restrict__ h0,
                                                const unsigned char* __restrict__ WhT4,
                                                const unsigned short* __restrict__ E2b,
                                                const int* __restrict__ caps,
                                                unsigned char* __restrict__ hA8){
    __shared__ __align__(32) unsigned char hl[2][HH];   // fp8 h, double-buffered (1 KB)
    int tid = threadIdx.x;
    int lane = tid & 63, wv = tid >> 6;      // 8 waves
    int l15 = lane & 15, lhi = lane >> 4;
    int n = blockIdx.x;
    int c0w = wv*64;                         // 64 cols per wave
    int mycol = c0w + lane;                  // col this lane finishes (ct==lhi)

    // B fragments: Wh fp4, register-resident (pinned): 4 ct x 4 kt x 16 B
    int4v b[4][4];
    #pragma unroll
    for (int ct = 0; ct < 4; ++ct){
        int col = c0w + ct*16 + l15;
        #pragma unroll
        for (int kt = 0; kt < 4; ++kt){
            b[ct][kt] = *reinterpret_cast<const int4v*>(WhT4 + (size_t)col*256 + kt*64 + lhi*16);
            asm volatile("" : "+v"(b[ct][kt]));   // opaque: no remat / re-stream
        }
    }
    // init hl[0] from h0 (fp32 -> fp8), one col per thread
    hl[0][tid] = f2f8(h0[(size_t)n*HH + tid]);
    __syncthreads();
    int cur = 0;
    for (int t = 0; t < TT; ++t){
        int tok = caps[n*(TT+1) + t];
        unsigned short xv = E2b[(size_t)tok*HH + mycol];
        int8v a[4];
        #pragma unroll
        for (int kt = 0; kt < 4; ++kt)
            a[kt] = *reinterpret_cast<const int8v*>(&hl[cur][kt*128 + lhi*32]);
        f32x4 acc[4];
        #pragma unroll
        for (int ct = 0; ct < 4; ++ct){
            acc[ct] = (f32x4){0.f,0.f,0.f,0.f};
            #pragma unroll
            for (int kt = 0; kt < 4; ++kt){
                int8v bb = __builtin_shufflevector(b[ct][kt], b[ct][kt], 0,1,2,3,0,1,2,3);
                acc[ct] = __builtin_amdgcn_mfma_scale_f32_16x16x128_f8f6f4(
                    a[kt], bb, acc[ct],
                    0, 4,                        // cbsz=fp8(A), blgp=fp4(B)
                    0, (int)0x7F7F7F7F,          // A scale 2^0
                    0, (int)0x7A7A7A7A);         // B scale 2^-5
            }
        }
        float v = (lhi == 0) ? acc[0][0] : (lhi == 1) ? acc[1][0]
                : (lhi == 2) ? acc[2][0] : acc[3][0];
        float x = v + bf2f(xv);
        float e = __expf(2.f*x);
        float th = 1.f - 2.f/(e + 1.f);          // tanh(x), saturates correctly
        unsigned char hv = f2f8(th);
        hl[cur^1][mycol] = hv;
        hA8[((size_t)n*TT + t)*HH + mycol] = hv;
        __syncthreads();
        cur ^= 1;
    }
}

// ---------- scores: MX-fp8 GEMM, T3/T4 2-deep pipeline: double-buffered LDS, raw
//             s_barrier + COUNTED s_waitcnt vmcnt(8) (never 0 in-loop) so next-tile
//             loads stay in flight across the entire ds_read+MFMA phase. Safety:
//             top-of-iter barrier = all waves consumed buf^1 (their ds_reads are
//             register-consumed before reaching it); per-wave vmcnt(8) = own buf-cur
//             stores landed (8 = loads issued this iter). Epilogue unchanged.
__global__ __launch_bounds__(256) void k_scores(const unsigned char* __restrict__ hA8,
                                                const unsigned char* __restrict__ WoT8p,
                                                const float* __restrict__ bop,
                                                const int* __restrict__ caps,
                                                float* __restrict__ pps,   // [NCT][MROWS]
                                                float* __restrict__ pts){  // [NCT][MROWS]
    __shared__ unsigned char As[2][128*128];   // 2 x 16 KB
    __shared__ unsigned char Bs[2][128*128];   // 2 x 16 KB
    int bid = blockIdx.x;
    int x = bid & 7;                 // XCD (blocks round-robin across XCDs)
    int local = bid >> 3;            // 0..1263
    int ct = local >> 4;             // ct-major within XCD
    int rt = x*16 + (local & 15);    // rt-minor: 16 consecutive row-tiles per XCD

    int tid = threadIdx.x;
    int lane = tid & 63, wv = tid >> 6;
    int l15 = lane & 15, lhi = lane >> 4;
    int wr = wv >> 1, wc = wv & 1;
    const size_t Abase = (size_t)rt*128*HH;
    const size_t Bbase = (size_t)ct*128*HH;

    unsigned srow[4], selem[4];
    #pragma unroll
    for (int i = 0; i < 4; ++i){
        unsigned chunk = (unsigned)(i*256 + tid);
        srow[i]  = chunk >> 3;
        selem[i] = ((chunk & 7u) ^ (srow[i] & 7u)) * 16u;
    }

    // prologue: stage kt=0 into buffer 0 (8 loads/thread, left in flight)
    #pragma unroll
    for (int i = 0; i < 4; ++i){
        gload16b(hA8   + Abase + (size_t)srow[i]*HH + selem[i], &As[0][(unsigned)((i*256 + wv*64) * 16)]);
        gload16b(WoT8p + Bbase + (size_t)srow[i]*HH + selem[i], &Bs[0][(unsigned)((i*256 + wv*64) * 16)]);
    }

    f32x4 acc[4][4];
    #pragma unroll
    for (int m = 0; m < 4; ++m)
        #pragma unroll
        for (int n = 0; n < 4; ++n)
            acc[m][n] = (f32x4){0.f,0.f,0.f,0.f};

    #pragma unroll
    for (int kt = 0; kt < 4; ++kt){
        const int cb = kt & 1, nb = cb ^ 1;
        __builtin_amdgcn_s_barrier();      // raw: no vmcnt drain
        if (kt < 3){
            #pragma unroll
            for (int i = 0; i < 4; ++i){
                gload16b(hA8   + Abase + (size_t)srow[i]*HH + (kt+1)*128 + selem[i],
                         &As[nb][(unsigned)((i*256 + wv*64) * 16)]);
                gload16b(WoT8p + Bbase + (size_t)srow[i]*HH + (kt+1)*128 + selem[i],
                         &Bs[nb][(unsigned)((i*256 + wv*64) * 16)]);
            }
            asm volatile("s_waitcnt vmcnt(8)" ::: "memory");  // buf-cur done; 8 next-tile in flight
        } else {
            asm volatile("s_waitcnt vmcnt(0)" ::: "memory");  // last tile: drain
        }
        int8v af[4], bf[4];
        #pragma unroll
        for (int m = 0; m < 4; ++m){
            unsigned row = (unsigned)(wr*64 + m*16 + l15);
            int4v c0 = *reinterpret_cast<const int4v*>(&As[cb][row*128 + (((unsigned)(lhi*2+0) ^ (row&7))*16)]);
            int4v c1 = *reinterpret_cast<const int4v*>(&As[cb][row*128 + (((unsigned)(lhi*2+1) ^ (row&7))*16)]);
            af[m] = __builtin_shufflevector(c0, c1, 0,1,2,3,4,5,6,7);
        }
        #pragma unroll
        for (int n = 0; n < 4; ++n){
            unsigned col = (unsigned)(wc*64 + n*16 + l15);
            int4v c0 = *reinterpret_cast<const int4v*>(&Bs[cb][col*128 + (((unsigned)(lhi*2+0) ^ (col&7))*16)]);
            int4v c1 = *reinterpret_cast<const int4v*>(&Bs[cb][col*128 + (((unsigned)(lhi*2+1) ^ (col&7))*16)]);
            bf[n] = __builtin_shufflevector(c0, c1, 0,1,2,3,4,5,6,7);
        }
        __builtin_amdgcn_s_setprio(1);
        #pragma unroll
        for (int m = 0; m < 4; ++m)
            #pragma unroll
            for (int n = 0; n < 4; ++n)
                acc[m][n] = __builtin_amdgcn_mfma_scale_f32_16x16x128_f8f6f4(
                    af[m], bf[n], acc[m][n],
                    0, 0,
                    0, (int)0x7F7F7F7F,
                    0, (int)0x7F7F7F7F);
        __builtin_amdgcn_s_setprio(0);
    }

    int tg[4][4];
    float srun[4][4], ts[4][4];
    #pragma unroll
    for (int m = 0; m < 4; ++m)
        #pragma unroll
        for (int r = 0; r < 4; ++r){
            int gr = rt*128 + wr*64 + m*16 + lhi*4 + r;
            tg[m][r] = caps[(gr >> 6)*(TT+1) + (gr & 63) + 1];
            srun[m][r] = 0.f; ts[m][r] = 0.f;
        }
    #pragma unroll
    for (int n = 0; n < 4; ++n){
        int colg = ct*128 + wc*64 + n*16 + l15;
        float bb = bop[colg];
        #pragma unroll
        for (int m = 0; m < 4; ++m)
            #pragma unroll
            for (int r = 0; r < 4; ++r){
                float sc = acc[m][n][r] + bb;
                srun[m][r] += __expf(sc);
                if (tg[m][r] == colg) ts[m][r] += sc;
            }
    }
    #pragma unroll
    for (int off = 1; off < 16; off <<= 1)
        #pragma unroll
        for (int m = 0; m < 4; ++m)
            #pragma unroll
            for (int r = 0; r < 4; ++r){
                srun[m][r] += __shfl_xor(srun[m][r], off, 64);
                ts[m][r]   += __shfl_xor(ts[m][r],   off, 64);
            }
    // cross-wc reduction: waves (wr,0) and (wr,1) hold partials for the SAME rows.
    __syncthreads();           // full drain before reusing As as scratch
    float* red = (float*)&As[0][0];   // 256 floats
    if (wc == 1 && l15 == 0){
        #pragma unroll
        for (int m = 0; m < 4; ++m)
            #pragma unroll
            for (int r = 0; r < 4; ++r){
                int ri = wr*64 + m*16 + lhi*4 + r;
                red[ri]       = srun[m][r];
                red[128 + ri] = ts[m][r];
            }
    }
    __syncthreads();
    if (wc == 0 && l15 == 0){
        #pragma unroll
        for (int m = 0; m < 4; ++m)
            #pragma unroll
            for (int r = 0; r < 4; ++r){
                int ri = wr*64 + m*16 + lhi*4 + r;
                int gr = rt*128 + ri;
                pps[(size_t)ct*MROWS + gr] = srun[m][r] + red[ri];
                pts[(size_t)ct*MROWS + gr] = ts[m][r]   + red[128 + ri];
            }
    }
}

// ---------- loss stage 1: per-row nll, block partial sums (64 blocks x 256 thr) ----------
__global__ __launch_bounds__(256) void k_loss1(const float* __restrict__ pps,
                                               const float* __restrict__ pts,
                                               const int* __restrict__ caps,
                                               float* __restrict__ bsum){
    __shared__ float red[256];
    int tid = threadIdx.x;
    int row = blockIdx.x*256 + tid;
    float s = 0.f, t0 = 0.f;
    for (int ct = 0; ct < NCT; ++ct){
        s  += pps[(size_t)ct*MROWS + row];
        t0 += pts[(size_t)ct*MROWS + row];
    }
    int tgt = caps[(row >> 6)*(TT+1) + (row & 63) + 1];
    red[tid] = (tgt != 0) ? (__logf(s) - t0) : 0.f;
    __syncthreads();
    for (int off = 128; off > 0; off >>= 1){
        if (tid < off) red[tid] += red[tid+off];
        __syncthreads();
    }
    if (tid == 0) bsum[blockIdx.x] = red[0];
}

// ---------- loss stage 2: final sum / N ----------
__global__ __launch_bounds__(64) void k_loss2(const float* __restrict__ bsum, float* __restrict__ out){
    __shared__ float red[64];
    int tid = threadIdx.x;
    red[tid] = bsum[tid];
    __syncthreads();
    for (int off = 32; off > 0; off >>= 1){
        if (tid < off) red[tid] += red[tid+off];
        __syncthreads();
    }
    if (tid == 0) out[0] = red[0] / (float)NB;
}

extern "C" void kernel_launch(void* const* d_in, const int* in_sizes, int n_in,
                              void* d_out, int out_size, void* d_ws, size_t ws_size,
                              hipStream_t stream) {
    const float* features = (const float*)d_in[0];
    const int*   captions = (const int*)  d_in[1];
    const float* W_proj   = (const float*)d_in[2];
    const float* b_proj   = (const float*)d_in[3];
    const float* W_embed  = (const float*)d_in[4];
    const float* Wx       = (const float*)d_in[5];
    const float* Wh       = (const float*)d_in[6];
    const float* b_       = (const float*)d_in[7];
    const float* W_out    = (const float*)d_in[8];
    const float* b_out    = (const float*)d_in[9];
    float* out = (float*)d_out;

    char* ws = (char*)d_ws;
    // byte offsets (256-aligned)
    unsigned short* E2b   = (unsigned short*)(ws + 0);           // 10000*512*2 = 10,240,000
    float*          h0    = (float*)         (ws + 10240000);    // 256*512*4   =    524,288
    unsigned char*  WhT4  = (unsigned char*) (ws + 10764288);    // 512*256     =    131,072
    unsigned short* WxT   = (unsigned short*)(ws + 10895360);    // 512*256*2   =    262,144
    unsigned char*  WoT8p = (unsigned char*) (ws + 11157504);    // 10112*512*1 =  5,177,344
    float*          bop   = (float*)         (ws + 16334848);    // 10112*4     =     40,448
    unsigned char*  hA8   = (unsigned char*) (ws + 16375296);    // 16384*512*1 =  8,388,608
    float*          pps   = (float*)         (ws + 24763904);    // 79*16384*4  =  5,177,344
    float*          pts   = (float*)         (ws + 29941248);    // 79*16384*4  =  5,177,344
    float*          bsum  = (float*)         (ws + 35118592);    // 64*4        =        256
    if (ws_size < 35118848u) return;

    k_transpose_bf<<<dim3(8, 16),  256, 0, stream>>>(Wx,    WxT,   WW, HH, HH);
    k_wh4<<<256, 512, 0, stream>>>(Wh, WhT4);
    k_transpose_f8<<<dim3(158,32), 256, 0, stream>>>(W_out, WoT8p, HH, VV, VP);
    k_biaspad<<<40, 256, 0, stream>>>(b_out, bop);
    k_h0<<<NB/4, 512, 0, stream>>>(features, W_proj, b_proj, h0);
    k_e2<<<157, 256, 0, stream>>>(W_embed, WxT, b_, E2b);
    k_rnn<<<NB, 512, 0, stream>>>(h0, WhT4, E2b, captions, hA8);
    k_scores<<<128*NCT, 256, 0, stream>>>(hA8, WoT8p, bop, captions, pps, pts);
    k_loss1<<<64, 256, 0, stream>>>(pps, pts, captions, bsum);
    k_loss2<<<1, 64, 0, stream>>>(bsum, out);
}